// Round 7
// baseline (134.776 us; speedup 1.0000x reference)
//
#include <hip/hip_runtime.h>

#define HH 16
#define DD 128
#define NBQ 128
#define SS 8192

typedef __attribute__((ext_vector_type(4))) float f32x4;
typedef __attribute__((ext_vector_type(4))) short bf16x4;
typedef __attribute__((ext_vector_type(8))) short bf16x8;

__device__ __forceinline__ unsigned short f2bf(float f) {
  unsigned u = __builtin_bit_cast(unsigned, f);
  u += 0x7fff + ((u >> 16) & 1);   // round-to-nearest-even
  return (unsigned short)(u >> 16);
}

__device__ __forceinline__ void gload_lds16(const void* g, void* l) {
  __builtin_amdgcn_global_load_lds(
      (const __attribute__((address_space(1))) void*)g,
      (__attribute__((address_space(3))) void*)l, 16, 0, 0);
}

// ---------------- prepass 1: K fp32 [s][h][d] -> bf16 [h][s][d] ----------------
__global__ __launch_bounds__(256)
void conv_k_kernel(const float* __restrict__ kg, unsigned short* __restrict__ kb) {
  const size_t e = ((size_t)blockIdx.x * 256 + threadIdx.x) * 4;  // out element idx
  const int h = (int)(e >> 20);           // S*D = 2^20
  const int s = (int)((e >> 7) & (SS - 1));
  const int d = (int)(e & 127);
  f32x4 a = *(const f32x4*)(kg + ((size_t)s * HH + h) * DD + d);
  bf16x4 o;
  o[0] = (short)f2bf(a[0]); o[1] = (short)f2bf(a[1]);
  o[2] = (short)f2bf(a[2]); o[3] = (short)f2bf(a[3]);
  *(bf16x4*)(kb + e) = o;
}

// ------- prepass 2: V fp32 [s][h][d] -> bf16 transposed blocks [h][kb][d][64] -------
__global__ __launch_bounds__(256)
void conv_vt_kernel(const float* __restrict__ vg, unsigned short* __restrict__ vt) {
  __shared__ unsigned short tile[128 * 72];  // [d][s'] with +8 short pad per row
  const int kb = blockIdx.x, h = blockIdx.y, tid = threadIdx.x;
  {
    const int r = tid >> 2, q = tid & 3;
    const float* vp = vg + ((size_t)(kb * 64 + r) * HH + h) * DD + q * 32;
    #pragma unroll
    for (int c = 0; c < 8; ++c) {
      f32x4 a = *(const f32x4*)(vp + c * 4);
      #pragma unroll
      for (int j = 0; j < 4; ++j) tile[(q * 32 + c * 4 + j) * 72 + r] = f2bf(a[j]);
    }
  }
  __syncthreads();
  const int d = tid >> 1, half = tid & 1;
  unsigned short* op = vt + ((size_t)(h * NBQ + kb) * 128 + d) * 64 + half * 32;
  #pragma unroll
  for (int j = 0; j < 4; ++j)
    *(bf16x8*)(op + j * 8) = *(const bf16x8*)(&tile[d * 72 + half * 32 + j * 8]);
}

// --------- main kernel: 1 workgroup = (4 q-blocks, head), 8 waves x 32 rows ---------
// Per-wave code identical to verified v5; only the wave->q-block mapping, KV list,
// staging split (512 threads), and P-buffer layout change.
// KV union list for q-blocks {4g..4g+3}: {0..3} u {max(4,4g-3) .. 4g+3}  (<=11 blocks),
// amortizing each 32KB staged K/V block over ~3x more MFMA than the 2-block version.
__global__ __launch_bounds__(512, 1)
void sparse_attn_v6(const float* __restrict__ qg_, const unsigned short* __restrict__ kbuf,
                    const unsigned short* __restrict__ vtbuf, float* __restrict__ outg) {
  extern __shared__ __align__(16) char lds[];
  // buf b (b=0,1): K at b*32768 ([64 key][128 d] bf16 swz) | Vt at +16384 ([128 d][64 key] swz)
  // P per-wave: 65536 + wid*4096  ([32 row][64 key] bf16 swz)   (8 waves -> 96KB total)

  const int qgrp = blockIdx.x;   // 0..31
  const int h    = blockIdx.y;
  const int tid  = threadIdx.x;
  const int wid  = tid >> 6;     // 0..7
  const int lane = tid & 63;
  const int l15  = lane & 15;
  const int lg   = lane >> 4;

  const int qlo  = qgrp * 4, qhi = qgrp * 4 + 3;
  const int qb_w = qlo + (wid >> 1);          // this wave's q-block (2 waves per block)
  const int rib0 = (wid & 1) * 32;            // wave's row base within its q-block

  const int nv     = 4;                        // qhi >= 3 always
  const int wstart = (qlo - 3 > 4) ? qlo - 3 : 4;
  const int nw     = (qhi - wstart + 1 > 0) ? qhi - wstart + 1 : 0;
  const int nlist  = nv + nw;                  // 4, 8, or 11

  char* Pl = lds + 65536 + wid * 4096;
  // 1/sqrt(128) * log2(e): exp2-domain softmax
  const float scale = 0.12752030522080552f;

  const int rowbase = qgrp * 256 + (wid >> 1) * 64 + (wid & 1) * 32;

  // ---- Q fragments (A operand), scale folded ----
  bf16x8 qa[2][4];
  #pragma unroll
  for (int m = 0; m < 2; ++m) {
    const float* qp = qg_ + ((size_t)(rowbase + m * 16 + l15) * HH + h) * DD;
    #pragma unroll
    for (int kc = 0; kc < 4; ++kc) {
      const int d0 = kc * 32 + lg * 8;
      f32x4 a = *(const f32x4*)(qp + d0);
      f32x4 b = *(const f32x4*)(qp + d0 + 4);
      bf16x8 f;
      f[0] = (short)f2bf(a[0] * scale); f[1] = (short)f2bf(a[1] * scale);
      f[2] = (short)f2bf(a[2] * scale); f[3] = (short)f2bf(a[3] * scale);
      f[4] = (short)f2bf(b[0] * scale); f[5] = (short)f2bf(b[1] * scale);
      f[6] = (short)f2bf(b[2] * scale); f[7] = (short)f2bf(b[3] * scale);
      qa[m][kc] = f;
    }
  }

  f32x4 oa[2][8];
  #pragma unroll
  for (int m = 0; m < 2; ++m)
    #pragma unroll
    for (int i = 0; i < 8; ++i) oa[m][i] = (f32x4){0.f, 0.f, 0.f, 0.f};
  float mr[2][4], lr[2][4];   // mr: row-uniform running max; lr: per-lane PARTIAL sum
  #pragma unroll
  for (int m = 0; m < 2; ++m)
    #pragma unroll
    for (int r = 0; r < 4; ++r) { mr[m][r] = -1e30f; lr[m][r] = 0.f; }

  const char* kbase = (const char*)kbuf + ((size_t)h * NBQ << 14);
  const char* vbase = (const char*)vtbuf + ((size_t)h * NBQ << 14);

  // prologue: stage list[0] (= block 0) into buf 0.  512 threads: 2 rounds x 8KB.
  {
    #pragma unroll
    for (int p = 0; p < 2; ++p) {
      const int ob = p * 8192 + wid * 1024;
      const int o  = ob + lane * 16;
      gload_lds16(kbase + (o ^ (((o >> 8) & 7) << 4)), lds + ob);
      gload_lds16(vbase + (o ^ (((o >> 7) & 7) << 4)), lds + 16384 + ob);
    }
  }
  __syncthreads();

  for (int t = 0; t < nlist; ++t) {
    // ---- prefetch t+1 into the other buffer ----
    if (t + 1 < nlist) {
      const int kbn = (t + 1 < nv) ? (t + 1) : (wstart + (t + 1 - nv));
      const char* ksrc = kbase + ((size_t)kbn << 14);
      const char* vsrc = vbase + ((size_t)kbn << 14);
      char* Kd = lds + ((t + 1) & 1) * 32768;
      #pragma unroll
      for (int p = 0; p < 2; ++p) {
        const int ob = p * 8192 + wid * 1024;
        const int o  = ob + lane * 16;
        gload_lds16(ksrc + (o ^ (((o >> 8) & 7) << 4)), Kd + ob);
        gload_lds16(vsrc + (o ^ (((o >> 7) & 7) << 4)), Kd + 16384 + ob);
      }
    }

    const int kb = (t < nv) ? t : (wstart + (t - nv));
    const bool valid = (kb <= qb_w) && ((qb_w - kb < 4) || (kb < 4));
    if (valid) {
      char* Kb = lds + (t & 1) * 32768;
      char* Vb = Kb + 16384;

      // ---- S = Q K^T : row q = lg*4+r, col key = n4*16+l15 (v2-verified) ----
      f32x4 s[2][4];
      #pragma unroll
      for (int m = 0; m < 2; ++m)
        #pragma unroll
        for (int n4 = 0; n4 < 4; ++n4) s[m][n4] = (f32x4){0.f, 0.f, 0.f, 0.f};
      __builtin_amdgcn_s_setprio(1);
      #pragma unroll
      for (int n4 = 0; n4 < 4; ++n4) {
        const int key = n4 * 16 + l15;
        #pragma unroll
        for (int kc = 0; kc < 4; ++kc) {
          const int off = (key * 256 + (kc * 32 + lg * 8) * 2) ^ ((key & 7) << 4);
          bf16x8 kf = *(const bf16x8*)(Kb + off);
          s[0][n4] = __builtin_amdgcn_mfma_f32_16x16x32_bf16(qa[0][kc], kf, s[0][n4], 0, 0, 0);
          s[1][n4] = __builtin_amdgcn_mfma_f32_16x16x32_bf16(qa[1][kc], kf, s[1][n4], 0, 0, 0);
        }
      }
      __builtin_amdgcn_s_setprio(0);

      // ---- diagonal block: element-level causal mask ----
      if (kb == qb_w) {
        #pragma unroll
        for (int m = 0; m < 2; ++m)
          #pragma unroll
          for (int n4 = 0; n4 < 4; ++n4) {
            const int key = n4 * 16 + l15;
            #pragma unroll
            for (int r = 0; r < 4; ++r) {
              const int rib = rib0 + m * 16 + lg * 4 + r;
              if (rib < key) s[m][n4][r] = -1e30f;
            }
          }
      }

      // ---- softmax: exp2 domain, defer-max THR=8, deferred sum ----
      #pragma unroll
      for (int m = 0; m < 2; ++m) {
        float pmax[4];
        #pragma unroll
        for (int r = 0; r < 4; ++r)
          pmax[r] = fmaxf(fmaxf(s[m][0][r], s[m][1][r]), fmaxf(s[m][2][r], s[m][3][r]));
        const int ok = (pmax[0] <= mr[m][0] + 8.f) & (pmax[1] <= mr[m][1] + 8.f) &
                       (pmax[2] <= mr[m][2] + 8.f) & (pmax[3] <= mr[m][3] + 8.f);
        if (!__all(ok)) {
          float sc[4];
          #pragma unroll
          for (int r = 0; r < 4; ++r) {
            float mx = pmax[r];
            mx = fmaxf(mx, __shfl_xor(mx, 1));
            mx = fmaxf(mx, __shfl_xor(mx, 2));
            mx = fmaxf(mx, __shfl_xor(mx, 4));
            mx = fmaxf(mx, __shfl_xor(mx, 8));   // row-uniform across l15
            const float mnew = fmaxf(mr[m][r], mx);
            sc[r] = __builtin_amdgcn_exp2f(mr[m][r] - mnew);
            mr[m][r] = mnew;
            lr[m][r] *= sc[r];                   // partial sums scale too
          }
          #pragma unroll
          for (int nd = 0; nd < 8; ++nd) {
            oa[m][nd][0] *= sc[0]; oa[m][nd][1] *= sc[1];
            oa[m][nd][2] *= sc[2]; oa[m][nd][3] *= sc[3];
          }
        }
        #pragma unroll
        for (int r = 0; r < 4; ++r) {
          float acc = 0.f;
          #pragma unroll
          for (int n4 = 0; n4 < 4; ++n4) {
            const float p = __builtin_amdgcn_exp2f(s[m][n4][r] - mr[m][r]);
            s[m][n4][r] = p;
            acc += p;
          }
          lr[m][r] += acc;   // lane-partial: no shuffles here
        }
      }

      // ---- P -> per-wave LDS (bf16, swz) for A-fragment transpose ----
      #pragma unroll
      for (int m = 0; m < 2; ++m)
        #pragma unroll
        for (int n4 = 0; n4 < 4; ++n4) {
          const int col = n4 * 16 + l15;
          #pragma unroll
          for (int r = 0; r < 4; ++r) {
            const int row = m * 16 + lg * 4 + r;
            const int off = (row * 128 + col * 2) ^ ((row & 7) << 4);
            *(short*)(Pl + off) = (short)f2bf(s[m][n4][r]);
          }
        }
      bf16x8 pa[2][2];
      #pragma unroll
      for (int m = 0; m < 2; ++m) {
        const int row = m * 16 + l15;
        #pragma unroll
        for (int kc = 0; kc < 2; ++kc) {
          const int off = (row * 128 + (kc * 32 + lg * 8) * 2) ^ ((row & 7) << 4);
          pa[m][kc] = *(const bf16x8*)(Pl + off);
        }
      }

      // ---- O += P V ----
      __builtin_amdgcn_s_setprio(1);
      #pragma unroll
      for (int nd = 0; nd < 8; ++nd) {
        const int d = nd * 16 + l15;
        #pragma unroll
        for (int kc = 0; kc < 2; ++kc) {
          const int off = (d * 128 + (kc * 32 + lg * 8) * 2) ^ ((d & 7) << 4);
          bf16x8 vf = *(const bf16x8*)(Vb + off);
          oa[0][nd] = __builtin_amdgcn_mfma_f32_16x16x32_bf16(pa[0][kc], vf, oa[0][nd], 0, 0, 0);
          oa[1][nd] = __builtin_amdgcn_mfma_f32_16x16x32_bf16(pa[1][kc], vf, oa[1][nd], 0, 0, 0);
        }
      }
      __builtin_amdgcn_s_setprio(0);
    }
    __syncthreads();  // drains prefetch vmcnt AND protects buffer reuse
  }

  // ---- epilogue: one sum-reduction per row, normalize, store fp32 ----
  #pragma unroll
  for (int m = 0; m < 2; ++m) {
    float inv[4];
    #pragma unroll
    for (int r = 0; r < 4; ++r) {
      float l = lr[m][r];
      l += __shfl_xor(l, 1);
      l += __shfl_xor(l, 2);
      l += __shfl_xor(l, 4);
      l += __shfl_xor(l, 8);
      inv[r] = 1.0f / l;
    }
    float* op = outg + ((size_t)(rowbase + m * 16) * HH + h) * DD;
    #pragma unroll
    for (int nd = 0; nd < 8; ++nd) {
      const int d = nd * 16 + l15;
      #pragma unroll
      for (int r = 0; r < 4; ++r) {
        const int qr = lg * 4 + r;
        op[(size_t)qr * HH * DD + d] = oa[m][nd][r] * inv[r];
      }
    }
  }
}

extern "C" void kernel_launch(void* const* d_in, const int* in_sizes, int n_in,
                              void* d_out, int out_size, void* d_ws, size_t ws_size,
                              hipStream_t stream) {
  const float* q = (const float*)d_in[0];
  const float* k = (const float*)d_in[1];
  const float* v = (const float*)d_in[2];
  float* out = (float*)d_out;
  const size_t elems = (size_t)HH * SS * DD;
  unsigned short* kbuf  = (unsigned short*)d_ws;
  unsigned short* vtbuf = kbuf + elems;

  conv_k_kernel<<<(int)(elems / 4 / 256), 256, 0, stream>>>(k, kbuf);
  conv_vt_kernel<<<dim3(NBQ, HH), 256, 0, stream>>>(v, vtbuf);
  sparse_attn_v6<<<dim3(NBQ / 4, HH), 512, 98304, stream>>>(q, kbuf, vtbuf, out);
}